// Round 1
// baseline (1241.318 us; speedup 1.0000x reference)
//
#include <hip/hip_runtime.h>
#include <math.h>

#define NNODES 100000
#define NEDGES 3200000
constexpr int CHUNK = 128;
constexpr int NCH = (NNODES + CHUNK - 1) / CHUNK; // 782

// ---------------- CSR build ----------------

__global__ void k_deg(const int* __restrict__ dst, int* __restrict__ deg) {
    int e = blockIdx.x * blockDim.x + threadIdx.x;
    if (e < NEDGES) atomicAdd(&deg[dst[e]], 1);
}

__global__ void k_chunksum(const int* __restrict__ deg, int* __restrict__ cs) {
    int c = blockIdx.x * blockDim.x + threadIdx.x;
    if (c >= NCH) return;
    int base = c * CHUNK, lim = min(CHUNK, NNODES - base), s = 0;
    for (int j = 0; j < lim; j++) s += deg[base + j];
    cs[c] = s;
}

__global__ void k_scan(const int* __restrict__ cs, int* __restrict__ co) {
    __shared__ int s[1024];
    int i = threadIdx.x;
    int v = (i < NCH) ? cs[i] : 0;
    s[i] = v;
    __syncthreads();
    for (int off = 1; off < 1024; off <<= 1) {
        int t = (i >= off) ? s[i - off] : 0;
        __syncthreads();
        s[i] += t;
        __syncthreads();
    }
    if (i < NCH) co[i] = s[i] - v;  // exclusive
}

__global__ void k_offsets(const int* __restrict__ deg, const int* __restrict__ co,
                          int* __restrict__ offs, float* __restrict__ deginv) {
    int c = blockIdx.x * blockDim.x + threadIdx.x;
    if (c >= NCH) return;
    int base = c * CHUNK, lim = min(CHUNK, NNODES - base), run = co[c];
    for (int j = 0; j < lim; j++) {
        int idx = base + j, d = deg[idx];
        offs[idx] = run;
        deginv[idx] = 1.0f / (float)max(d, 1);
        run += d;
    }
}

__global__ void k_fill(const int* __restrict__ src, const int* __restrict__ dst,
                       const int* __restrict__ offs, int* __restrict__ cursor,
                       int* __restrict__ csr) {
    int e = blockIdx.x * blockDim.x + threadIdx.x;
    if (e < NEDGES) {
        int d = dst[e];
        int slot = atomicAdd(&cursor[d], 1);
        csr[offs[d] + slot] = src[e];
    }
}

// ---------------- Layer 1: gather x (8f) -> h1 (64), fused t2 = h1 @ w2l ----------------

__global__ __launch_bounds__(256) void k_layer1(
    const float* __restrict__ x, const int* __restrict__ csr,
    const int* __restrict__ offs, const int* __restrict__ deg,
    const float* __restrict__ deginv,
    const float* __restrict__ w1l, const float* __restrict__ w1r,
    const float* __restrict__ b1,
    const float* __restrict__ g1, const float* __restrict__ bb1,
    const float* __restrict__ m1, const float* __restrict__ v1,
    const float* __restrict__ w2l,
    float* __restrict__ h1, float* __restrict__ t2)
{
    __shared__ float s_w1l[8 * 64], s_w1r[8 * 64], s_w2l[64 * 64];
    __shared__ float s_b1[64], s_g[64], s_bb[64], s_m[64], s_rstd[64];
    int tid = threadIdx.x;
    for (int i = tid; i < 8 * 64; i += 256) { s_w1l[i] = w1l[i]; s_w1r[i] = w1r[i]; }
    for (int i = tid; i < 64 * 64; i += 256) s_w2l[i] = w2l[i];
    if (tid < 64) {
        s_b1[tid] = b1[tid]; s_g[tid] = g1[tid]; s_bb[tid] = bb1[tid];
        s_m[tid] = m1[tid];  s_rstd[tid] = rsqrtf(v1[tid] + 1e-5f);
    }
    __syncthreads();
    int lane = tid & 63;
    int node = blockIdx.x * 4 + (tid >> 6);
    if (node >= NNODES) return;

    int f = lane & 7, g = lane >> 3;         // 8 edge-groups x 8 features
    int start = offs[node], d = deg[node];
    float acc = 0.f;
    for (int i = g; i < d; i += 8) {
        int s = csr[start + i];
        acc += x[s * 8 + f];
    }
    // reduce the 8 groups (xor over group bits 8,16,32) -> every lane holds agg[f]
    acc += __shfl_xor(acc, 8);
    acc += __shfl_xor(acc, 16);
    acc += __shfl_xor(acc, 32);
    acc *= deginv[node];
    float xs = x[node * 8 + f];

    // output feature o = lane
    float h = s_b1[lane];
#pragma unroll
    for (int k = 0; k < 8; k++) {
        float a  = __shfl(acc, k);
        float xv = __shfl(xs, k);
        h += a * s_w1l[k * 64 + lane] + xv * s_w1r[k * 64 + lane];
    }
    h = (h - s_m[lane]) * s_rstd[lane] * s_g[lane] + s_bb[lane];
    h = fmaxf(h, 0.f);
    h1[node * 64 + lane] = h;

    // t2 = h1row @ w2l  (pre-multiplied so layer2 aggregates t2 directly)
    float t = 0.f;
#pragma unroll
    for (int k = 0; k < 64; k++) {
        float hv = __shfl(h, k);
        t += hv * s_w2l[k * 64 + lane];
    }
    t2[node * 64 + lane] = t;
}

// ---------------- Layer 2: gather t2 (64f) -> h2 (64), fused t3 = h2 @ w3l ----------------

__global__ __launch_bounds__(256) void k_layer2(
    const float* __restrict__ t2, const float* __restrict__ h1,
    const int* __restrict__ csr, const int* __restrict__ offs,
    const int* __restrict__ deg, const float* __restrict__ deginv,
    const float* __restrict__ w2r, const float* __restrict__ b2,
    const float* __restrict__ g2, const float* __restrict__ bb2,
    const float* __restrict__ m2, const float* __restrict__ v2,
    const float* __restrict__ w3l,
    float* __restrict__ h2, float* __restrict__ t3)
{
    __shared__ float s_w2r[64 * 64], s_w3l[64 * 32];
    __shared__ float s_b[64], s_g[64], s_bb[64], s_m[64], s_rstd[64];
    int tid = threadIdx.x;
    for (int i = tid; i < 64 * 64; i += 256) s_w2r[i] = w2r[i];
    for (int i = tid; i < 64 * 32; i += 256) s_w3l[i] = w3l[i];
    if (tid < 64) {
        s_b[tid] = b2[tid]; s_g[tid] = g2[tid]; s_bb[tid] = bb2[tid];
        s_m[tid] = m2[tid]; s_rstd[tid] = rsqrtf(v2[tid] + 1e-5f);
    }
    __syncthreads();
    int lane = tid & 63;
    int node = blockIdx.x * 4 + (tid >> 6);
    if (node >= NNODES) return;

    int start = offs[node], d = deg[node];
    float acc = 0.f;  // lane = feature; 256B coalesced per edge
    for (int i = 0; i < d; i++) {
        int s = csr[start + i];
        acc += t2[s * 64 + lane];
    }
    acc *= deginv[node];

    float h1v = h1[node * 64 + lane];
    float h = acc + s_b[lane];
#pragma unroll
    for (int k = 0; k < 64; k++) {
        float hv = __shfl(h1v, k);
        h += hv * s_w2r[k * 64 + lane];
    }
    h = (h - s_m[lane]) * s_rstd[lane] * s_g[lane] + s_bb[lane];
    h = fmaxf(h, 0.f);
    h2[node * 64 + lane] = h;

    // t3 = h2row @ w3l (32 outputs; halves duplicate work, lanes<32 store)
    int j = lane & 31;
    float t = 0.f;
#pragma unroll
    for (int k = 0; k < 64; k++) {
        float hv = __shfl(h, k);
        t += hv * s_w3l[k * 32 + j];
    }
    if (lane < 32) t3[node * 32 + lane] = t;
}

// ---------------- Layer 3: gather t3 (32f) -> h3 (32) -> fc -> sigmoid ----------------

__global__ __launch_bounds__(256) void k_layer3(
    const float* __restrict__ t3, const float* __restrict__ h2,
    const int* __restrict__ csr, const int* __restrict__ offs,
    const int* __restrict__ deg, const float* __restrict__ deginv,
    const float* __restrict__ w3r, const float* __restrict__ b3,
    const float* __restrict__ fcw, const float* __restrict__ fcb,
    float* __restrict__ out)
{
    __shared__ float s_w3r[64 * 32];
    __shared__ float s_b3[32], s_fcw[32];
    __shared__ float s_fcb;
    int tid = threadIdx.x;
    for (int i = tid; i < 64 * 32; i += 256) s_w3r[i] = w3r[i];
    if (tid < 32) { s_b3[tid] = b3[tid]; s_fcw[tid] = fcw[tid]; }
    if (tid == 0) s_fcb = fcb[0];
    __syncthreads();
    int lane = tid & 63;
    int node = blockIdx.x * 4 + (tid >> 6);
    if (node >= NNODES) return;

    int o = lane & 31, half = lane >> 5;   // 2 edge-halves x 32 features
    int start = offs[node], d = deg[node];
    float acc = 0.f;
    for (int i = half; i < d; i += 2) {
        int s = csr[start + i];
        acc += t3[s * 32 + o];
    }
    acc += __shfl_xor(acc, 32);  // combine halves -> full agg[o] (incl. @w3l)
    acc *= deginv[node];

    float h2v = h2[node * 64 + lane];
    float h = acc + s_b3[o];
#pragma unroll
    for (int k = 0; k < 64; k++) {
        float hv = __shfl(h2v, k);
        h += hv * s_w3r[k * 32 + o];
    }
    h = fmaxf(h, 0.f);

    // fc: dot(h3, fcw) ; each 32-lane half holds the full 32-vector
    float p = h * s_fcw[o];
    p += __shfl_xor(p, 1);
    p += __shfl_xor(p, 2);
    p += __shfl_xor(p, 4);
    p += __shfl_xor(p, 8);
    p += __shfl_xor(p, 16);
    if (lane == 0) {
        float z = p + s_fcb;
        out[node] = 1.0f / (1.0f + expf(-z));
    }
}

// ---------------- launch ----------------

extern "C" void kernel_launch(void* const* d_in, const int* in_sizes, int n_in,
                              void* d_out, int out_size, void* d_ws, size_t ws_size,
                              hipStream_t stream)
{
    const float* x   = (const float*)d_in[0];
    const int*   ei  = (const int*)d_in[1];
    const int*   src = ei;
    const int*   dst = ei + NEDGES;
    const float* w1l = (const float*)d_in[2];
    const float* w1r = (const float*)d_in[3];
    const float* b1  = (const float*)d_in[4];
    const float* g1  = (const float*)d_in[5];
    const float* bb1 = (const float*)d_in[6];
    const float* m1  = (const float*)d_in[7];
    const float* v1  = (const float*)d_in[8];
    const float* w2l = (const float*)d_in[9];
    const float* w2r = (const float*)d_in[10];
    const float* b2  = (const float*)d_in[11];
    const float* g2  = (const float*)d_in[12];
    const float* bb2 = (const float*)d_in[13];
    const float* m2  = (const float*)d_in[14];
    const float* v2  = (const float*)d_in[15];
    const float* w3l = (const float*)d_in[16];
    const float* w3r = (const float*)d_in[17];
    const float* b3  = (const float*)d_in[18];
    const float* fcw = (const float*)d_in[19];
    const float* fcb = (const float*)d_in[20];

    char* ws = (char*)d_ws;
    size_t off = 0;
    auto alloc = [&](size_t bytes) -> void* {
        void* p = ws + off;
        off += (bytes + 255) & ~(size_t)255;
        return p;
    };
    int*   deg    = (int*)alloc((size_t)NNODES * 4);
    int*   cursor = (int*)alloc((size_t)NNODES * 4);
    int*   offs   = (int*)alloc((size_t)NNODES * 4);
    int*   cs     = (int*)alloc((size_t)NCH * 4);
    int*   co     = (int*)alloc((size_t)NCH * 4);
    float* deginv = (float*)alloc((size_t)NNODES * 4);
    int*   csr    = (int*)alloc((size_t)NEDGES * 4);
    float* h1     = (float*)alloc((size_t)NNODES * 64 * 4);
    float* t2     = (float*)alloc((size_t)NNODES * 64 * 4);
    float* h2     = (float*)alloc((size_t)NNODES * 64 * 4);
    float* t3     = (float*)alloc((size_t)NNODES * 32 * 4);

    hipMemsetAsync(deg, 0, (size_t)NNODES * 4, stream);
    hipMemsetAsync(cursor, 0, (size_t)NNODES * 4, stream);

    k_deg<<<(NEDGES + 255) / 256, 256, 0, stream>>>(dst, deg);
    k_chunksum<<<(NCH + 255) / 256, 256, 0, stream>>>(deg, cs);
    k_scan<<<1, 1024, 0, stream>>>(cs, co);
    k_offsets<<<(NCH + 255) / 256, 256, 0, stream>>>(deg, co, offs, deginv);
    k_fill<<<(NEDGES + 255) / 256, 256, 0, stream>>>(src, dst, offs, cursor, csr);

    int nb = (NNODES + 3) / 4;
    k_layer1<<<nb, 256, 0, stream>>>(x, csr, offs, deg, deginv,
                                     w1l, w1r, b1, g1, bb1, m1, v1, w2l, h1, t2);
    k_layer2<<<nb, 256, 0, stream>>>(t2, h1, csr, offs, deg, deginv,
                                     w2r, b2, g2, bb2, m2, v2, w3l, h2, t3);
    k_layer3<<<nb, 256, 0, stream>>>(t3, h2, csr, offs, deg, deginv,
                                     w3r, b3, fcw, fcb, (float*)d_out);
}

// Round 2
// 960.509 us; speedup vs baseline: 1.2924x; 1.2924x over previous
//
#include <hip/hip_runtime.h>
#include <hip/hip_bf16.h>
#include <math.h>

#define NNODES 100000
#define NEDGES 3200000
constexpr int CHUNK = 128;
constexpr int NCH = (NNODES + CHUNK - 1) / CHUNK; // 782

typedef __hip_bfloat16 bf16;
__device__ __forceinline__ float b2f(bf16 v) { return __bfloat162float(v); }
__device__ __forceinline__ bf16 f2b(float v) { return __float2bfloat16(v); }

// ---------------- CSR build ----------------

__global__ void k_deg(const int* __restrict__ dst, int* __restrict__ deg) {
    int e = blockIdx.x * blockDim.x + threadIdx.x;
    if (e < NEDGES) atomicAdd(&deg[dst[e]], 1);
}

__global__ void k_chunksum(const int* __restrict__ deg, int* __restrict__ cs) {
    int c = blockIdx.x * blockDim.x + threadIdx.x;
    if (c >= NCH) return;
    int base = c * CHUNK, lim = min(CHUNK, NNODES - base), s = 0;
    for (int j = 0; j < lim; j++) s += deg[base + j];
    cs[c] = s;
}

__global__ void k_scan(const int* __restrict__ cs, int* __restrict__ co) {
    __shared__ int s[1024];
    int i = threadIdx.x;
    int v = (i < NCH) ? cs[i] : 0;
    s[i] = v;
    __syncthreads();
    for (int off = 1; off < 1024; off <<= 1) {
        int t = (i >= off) ? s[i - off] : 0;
        __syncthreads();
        s[i] += t;
        __syncthreads();
    }
    if (i < NCH) co[i] = s[i] - v;  // exclusive
}

__global__ void k_offsets(const int* __restrict__ deg, const int* __restrict__ co,
                          int* __restrict__ offs, float* __restrict__ deginv) {
    int c = blockIdx.x * blockDim.x + threadIdx.x;
    if (c >= NCH) return;
    int base = c * CHUNK, lim = min(CHUNK, NNODES - base), run = co[c];
    for (int j = 0; j < lim; j++) {
        int idx = base + j, d = deg[idx];
        offs[idx] = run;
        deginv[idx] = 1.0f / (float)max(d, 1);
        run += d;
    }
}

__global__ void k_fill(const int* __restrict__ src, const int* __restrict__ dst,
                       const int* __restrict__ offs, int* __restrict__ cursor,
                       int* __restrict__ csr) {
    int e = blockIdx.x * blockDim.x + threadIdx.x;
    if (e < NEDGES) {
        int d = dst[e];
        int slot = atomicAdd(&cursor[d], 1);
        csr[offs[d] + slot] = src[e];
    }
}

// ---------------- Layer 1: gather x (8f) -> h1 (64), fused t2 = h1 @ w2l (bf16) ----------------

__global__ __launch_bounds__(512) void k_layer1(
    const float* __restrict__ x, const int* __restrict__ csr,
    const int* __restrict__ offs, const float* __restrict__ deginv,
    const float* __restrict__ w1l, const float* __restrict__ w1r,
    const float* __restrict__ b1,
    const float* __restrict__ g1, const float* __restrict__ bb1,
    const float* __restrict__ m1, const float* __restrict__ v1,
    const float* __restrict__ w2l,
    float* __restrict__ h1, bf16* __restrict__ t2)
{
    __shared__ float s_w1l[8 * 64], s_w1r[8 * 64], s_w2l[64 * 64];
    __shared__ float s_b1[64], s_g[64], s_bb[64], s_m[64], s_rstd[64];
    int tid = threadIdx.x;
    for (int i = tid; i < 8 * 64; i += 512) { s_w1l[i] = w1l[i]; s_w1r[i] = w1r[i]; }
    for (int i = tid; i < 64 * 64; i += 512) s_w2l[i] = w2l[i];
    if (tid < 64) {
        s_b1[tid] = b1[tid]; s_g[tid] = g1[tid]; s_bb[tid] = bb1[tid];
        s_m[tid] = m1[tid];  s_rstd[tid] = rsqrtf(v1[tid] + 1e-5f);
    }
    __syncthreads();
    int lane = tid & 63;
    int node = blockIdx.x * 8 + (tid >> 6);
    if (node >= NNODES) return;

    int f = lane & 7, g = lane >> 3;         // 8 edge-groups x 8 features
    int start = offs[node];
    int dd = __ldg(&offs[node + 1 < NNODES ? node + 1 : node]);  // unused fallback
    (void)dd;
    // degree from deginv would be lossy; recompute via offs diff not stored; load deg via csr span:
    // we pass deg implicitly: use next offset trick is unsafe for last node, so read deginv + loop bound via d array
    // -> keep explicit: caller passes deg through offs? Simplest: encode d = offs[node+1]-offs[node] with sentinel.
    // (offs has NNODES entries; we add a sentinel written by k_offsets_sentinel below.)
    int d = __ldg(&offs[node + 1]) - start;

    float a0 = 0.f, a1 = 0.f;
    int i = g;
    for (; i + 8 < d; i += 16) {
        int s0 = csr[start + i], s1 = csr[start + i + 8];
        a0 += x[s0 * 8 + f];
        a1 += x[s1 * 8 + f];
    }
    for (; i < d; i += 8) a0 += x[csr[start + i] * 8 + f];
    float acc = a0 + a1;
    acc += __shfl_xor(acc, 8);
    acc += __shfl_xor(acc, 16);
    acc += __shfl_xor(acc, 32);
    acc *= deginv[node];
    float xs = x[node * 8 + f];

    float h = s_b1[lane];
#pragma unroll
    for (int k = 0; k < 8; k++) {
        float a  = __shfl(acc, k);
        float xv = __shfl(xs, k);
        h += a * s_w1l[k * 64 + lane] + xv * s_w1r[k * 64 + lane];
    }
    h = (h - s_m[lane]) * s_rstd[lane] * s_g[lane] + s_bb[lane];
    h = fmaxf(h, 0.f);
    h1[node * 64 + lane] = h;

    float t = 0.f;
#pragma unroll
    for (int k = 0; k < 64; k++) {
        float hv = __shfl(h, k);
        t += hv * s_w2l[k * 64 + lane];
    }
    t2[node * 64 + lane] = f2b(t);
}

// ---------------- Layer 2: gather t2 (64f bf16) -> h2 (64), fused t3 = h2 @ w3l (bf16) -----

__global__ __launch_bounds__(512) void k_layer2(
    const bf16* __restrict__ t2, const float* __restrict__ h1,
    const int* __restrict__ csr, const int* __restrict__ offs,
    const float* __restrict__ deginv,
    const float* __restrict__ w2r, const float* __restrict__ b2,
    const float* __restrict__ g2, const float* __restrict__ bb2,
    const float* __restrict__ m2, const float* __restrict__ v2,
    const float* __restrict__ w3l,
    float* __restrict__ h2, bf16* __restrict__ t3)
{
    __shared__ float s_w2r[64 * 64], s_w3l[64 * 32];
    __shared__ float s_b[64], s_g[64], s_bb[64], s_m[64], s_rstd[64];
    int tid = threadIdx.x;
    for (int i = tid; i < 64 * 64; i += 512) s_w2r[i] = w2r[i];
    for (int i = tid; i < 64 * 32; i += 512) s_w3l[i] = w3l[i];
    if (tid < 64) {
        s_b[tid] = b2[tid]; s_g[tid] = g2[tid]; s_bb[tid] = bb2[tid];
        s_m[tid] = m2[tid]; s_rstd[tid] = rsqrtf(v2[tid] + 1e-5f);
    }
    __syncthreads();
    int lane = tid & 63;
    int node = blockIdx.x * 8 + (tid >> 6);
    if (node >= NNODES) return;

    int start = offs[node];
    int d = offs[node + 1] - start;

    float a0 = 0.f, a1 = 0.f, a2 = 0.f, a3 = 0.f;
    int i = 0;
    for (; i + 4 <= d; i += 4) {
        int s0 = csr[start + i],     s1 = csr[start + i + 1];
        int s2 = csr[start + i + 2], s3 = csr[start + i + 3];
        a0 += b2f(t2[s0 * 64 + lane]);
        a1 += b2f(t2[s1 * 64 + lane]);
        a2 += b2f(t2[s2 * 64 + lane]);
        a3 += b2f(t2[s3 * 64 + lane]);
    }
    for (; i < d; i++) a0 += b2f(t2[csr[start + i] * 64 + lane]);
    float acc = ((a0 + a1) + (a2 + a3)) * deginv[node];

    float h1v = h1[node * 64 + lane];
    float h = acc + s_b[lane];
#pragma unroll
    for (int k = 0; k < 64; k++) {
        float hv = __shfl(h1v, k);
        h += hv * s_w2r[k * 64 + lane];
    }
    h = (h - s_m[lane]) * s_rstd[lane] * s_g[lane] + s_bb[lane];
    h = fmaxf(h, 0.f);
    h2[node * 64 + lane] = h;

    int j = lane & 31;
    float t = 0.f;
#pragma unroll
    for (int k = 0; k < 64; k++) {
        float hv = __shfl(h, k);
        t += hv * s_w3l[k * 32 + j];
    }
    if (lane < 32) t3[node * 32 + lane] = f2b(t);
}

// ---------------- Layer 3: gather t3 (32f bf16) -> h3 (32) -> fc -> sigmoid ----------------

__global__ __launch_bounds__(512) void k_layer3(
    const bf16* __restrict__ t3, const float* __restrict__ h2,
    const int* __restrict__ csr, const int* __restrict__ offs,
    const float* __restrict__ deginv,
    const float* __restrict__ w3r, const float* __restrict__ b3,
    const float* __restrict__ fcw, const float* __restrict__ fcb,
    float* __restrict__ out)
{
    __shared__ float s_w3r[64 * 32];
    __shared__ float s_b3[32], s_fcw[32];
    __shared__ float s_fcb;
    int tid = threadIdx.x;
    for (int i = tid; i < 64 * 32; i += 512) s_w3r[i] = w3r[i];
    if (tid < 32) { s_b3[tid] = b3[tid]; s_fcw[tid] = fcw[tid]; }
    if (tid == 0) s_fcb = fcb[0];
    __syncthreads();
    int lane = tid & 63;
    int node = blockIdx.x * 8 + (tid >> 6);
    if (node >= NNODES) return;

    int o = lane & 31, half = lane >> 5;   // 2 edge-halves x 32 features
    int start = offs[node];
    int d = offs[node + 1] - start;

    float a0 = 0.f, a1 = 0.f, a2 = 0.f, a3 = 0.f;
    int i = half;
    for (; i + 6 < d; i += 8) {
        int s0 = csr[start + i],     s1 = csr[start + i + 2];
        int s2 = csr[start + i + 4], s3 = csr[start + i + 6];
        a0 += b2f(t3[s0 * 32 + o]);
        a1 += b2f(t3[s1 * 32 + o]);
        a2 += b2f(t3[s2 * 32 + o]);
        a3 += b2f(t3[s3 * 32 + o]);
    }
    for (; i < d; i += 2) a0 += b2f(t3[csr[start + i] * 32 + o]);
    float acc = (a0 + a1) + (a2 + a3);
    acc += __shfl_xor(acc, 32);
    acc *= deginv[node];

    float h2v = h2[node * 64 + lane];
    float h = acc + s_b3[o];
#pragma unroll
    for (int k = 0; k < 64; k++) {
        float hv = __shfl(h2v, k);
        h += hv * s_w3r[k * 32 + o];
    }
    h = fmaxf(h, 0.f);

    float p = h * s_fcw[o];
    p += __shfl_xor(p, 1);
    p += __shfl_xor(p, 2);
    p += __shfl_xor(p, 4);
    p += __shfl_xor(p, 8);
    p += __shfl_xor(p, 16);
    if (lane == 0) {
        float z = p + s_fcb;
        out[node] = 1.0f / (1.0f + expf(-z));
    }
}

// sentinel writer: offs[NNODES] = NEDGES so d = offs[n+1]-offs[n] works for all n
__global__ void k_sentinel(int* __restrict__ offs) {
    if (threadIdx.x == 0 && blockIdx.x == 0) offs[NNODES] = NEDGES;
}

// ---------------- launch ----------------

extern "C" void kernel_launch(void* const* d_in, const int* in_sizes, int n_in,
                              void* d_out, int out_size, void* d_ws, size_t ws_size,
                              hipStream_t stream)
{
    const float* x   = (const float*)d_in[0];
    const int*   ei  = (const int*)d_in[1];
    const int*   src = ei;
    const int*   dst = ei + NEDGES;
    const float* w1l = (const float*)d_in[2];
    const float* w1r = (const float*)d_in[3];
    const float* b1  = (const float*)d_in[4];
    const float* g1  = (const float*)d_in[5];
    const float* bb1 = (const float*)d_in[6];
    const float* m1  = (const float*)d_in[7];
    const float* v1  = (const float*)d_in[8];
    const float* w2l = (const float*)d_in[9];
    const float* w2r = (const float*)d_in[10];
    const float* b2  = (const float*)d_in[11];
    const float* g2  = (const float*)d_in[12];
    const float* bb2 = (const float*)d_in[13];
    const float* m2  = (const float*)d_in[14];
    const float* v2  = (const float*)d_in[15];
    const float* w3l = (const float*)d_in[16];
    const float* w3r = (const float*)d_in[17];
    const float* b3  = (const float*)d_in[18];
    const float* fcw = (const float*)d_in[19];
    const float* fcb = (const float*)d_in[20];

    char* ws = (char*)d_ws;
    size_t off = 0;
    auto alloc = [&](size_t bytes) -> void* {
        void* p = ws + off;
        off += (bytes + 255) & ~(size_t)255;
        return p;
    };
    int*   deg    = (int*)alloc((size_t)NNODES * 4);
    int*   cursor = (int*)alloc((size_t)NNODES * 4);
    int*   offs   = (int*)alloc((size_t)(NNODES + 1) * 4);  // +1 sentinel
    int*   cs     = (int*)alloc((size_t)NCH * 4);
    int*   co     = (int*)alloc((size_t)NCH * 4);
    float* deginv = (float*)alloc((size_t)NNODES * 4);
    int*   csr    = (int*)alloc((size_t)NEDGES * 4);
    float* h1     = (float*)alloc((size_t)NNODES * 64 * 4);
    bf16*  t2     = (bf16*)alloc((size_t)NNODES * 64 * 2);
    float* h2     = (float*)alloc((size_t)NNODES * 64 * 4);
    bf16*  t3     = (bf16*)alloc((size_t)NNODES * 32 * 2);

    hipMemsetAsync(deg, 0, (size_t)NNODES * 4, stream);
    hipMemsetAsync(cursor, 0, (size_t)NNODES * 4, stream);

    k_deg<<<(NEDGES + 255) / 256, 256, 0, stream>>>(dst, deg);
    k_chunksum<<<(NCH + 255) / 256, 256, 0, stream>>>(deg, cs);
    k_scan<<<1, 1024, 0, stream>>>(cs, co);
    k_offsets<<<(NCH + 255) / 256, 256, 0, stream>>>(deg, co, offs, deginv);
    k_sentinel<<<1, 64, 0, stream>>>(offs);
    k_fill<<<(NEDGES + 255) / 256, 256, 0, stream>>>(src, dst, offs, cursor, csr);

    int nb = (NNODES + 7) / 8;
    k_layer1<<<nb, 512, 0, stream>>>(x, csr, offs, deginv,
                                     w1l, w1r, b1, g1, bb1, m1, v1, w2l, h1, t2);
    k_layer2<<<nb, 512, 0, stream>>>(t2, h1, csr, offs, deginv,
                                     w2r, b2, g2, bb2, m2, v2, w3l, h2, t3);
    k_layer3<<<nb, 512, 0, stream>>>(t3, h2, csr, offs, deginv,
                                     w3r, b3, fcw, fcb, (float*)d_out);
}

// Round 3
// 902.208 us; speedup vs baseline: 1.3759x; 1.0646x over previous
//
#include <hip/hip_runtime.h>
#include <hip/hip_bf16.h>
#include <math.h>

#define NNODES 100000
#define NEDGES 3200000
constexpr int CHUNK = 128;
constexpr int NCH = (NNODES + CHUNK - 1) / CHUNK; // 782

typedef __hip_bfloat16 bf16;
__device__ __forceinline__ bf16 f2b(float v) { return __float2bfloat16(v); }
__device__ __forceinline__ float lo2f(unsigned u) { return __uint_as_float(u << 16); }
__device__ __forceinline__ float hi2f(unsigned u) { return __uint_as_float(u & 0xffff0000u); }

// 8-way compile-time-tree select: returns a[c], c in 0..7
__device__ __forceinline__ float sel8(int c, float a0, float a1, float a2, float a3,
                                      float a4, float a5, float a6, float a7) {
    float b0 = (c & 1) ? a1 : a0, b2 = (c & 1) ? a3 : a2;
    float b4 = (c & 1) ? a5 : a4, b6 = (c & 1) ? a7 : a6;
    float c0 = (c & 2) ? b2 : b0, c4 = (c & 2) ? b6 : b4;
    return (c & 4) ? c4 : c0;
}

// ---------------- CSR build ----------------

__global__ void k_deg(const int4* __restrict__ dst4, int* __restrict__ deg) {
    int e = blockIdx.x * blockDim.x + threadIdx.x;
    if (e < NEDGES / 4) {
        int4 d = dst4[e];
        atomicAdd(&deg[d.x], 1);
        atomicAdd(&deg[d.y], 1);
        atomicAdd(&deg[d.z], 1);
        atomicAdd(&deg[d.w], 1);
    }
}

__global__ void k_chunksum(const int* __restrict__ deg, int* __restrict__ cs) {
    int c = blockIdx.x * blockDim.x + threadIdx.x;
    if (c >= NCH) return;
    int base = c * CHUNK, lim = min(CHUNK, NNODES - base), s = 0;
    for (int j = 0; j < lim; j++) s += deg[base + j];
    cs[c] = s;
}

__global__ void k_scan(const int* __restrict__ cs, int* __restrict__ co) {
    __shared__ int s[1024];
    int i = threadIdx.x;
    int v = (i < NCH) ? cs[i] : 0;
    s[i] = v;
    __syncthreads();
    for (int off = 1; off < 1024; off <<= 1) {
        int t = (i >= off) ? s[i - off] : 0;
        __syncthreads();
        s[i] += t;
        __syncthreads();
    }
    if (i < NCH) co[i] = s[i] - v;  // exclusive
}

__global__ void k_offsets(const int* __restrict__ deg, const int* __restrict__ co,
                          int* __restrict__ offs, float* __restrict__ deginv) {
    int c = blockIdx.x * blockDim.x + threadIdx.x;
    if (c >= NCH) return;
    int base = c * CHUNK, lim = min(CHUNK, NNODES - base), run = co[c];
    for (int j = 0; j < lim; j++) {
        int idx = base + j, d = deg[idx];
        offs[idx] = run;
        deginv[idx] = 1.0f / (float)max(d, 1);
        run += d;
    }
}

__global__ void k_sentinel(int* __restrict__ offs) {
    if (threadIdx.x == 0 && blockIdx.x == 0) offs[NNODES] = NEDGES;
}

// consumes deg (atomicSub down to 0) — no cursor array / extra memset
__global__ void k_fill(const int4* __restrict__ src4, const int4* __restrict__ dst4,
                       const int* __restrict__ offs, int* __restrict__ deg,
                       int* __restrict__ csr) {
    int e = blockIdx.x * blockDim.x + threadIdx.x;
    if (e < NEDGES / 4) {
        int4 s = src4[e];
        int4 d = dst4[e];
        int t;
        t = atomicSub(&deg[d.x], 1) - 1; csr[offs[d.x] + t] = s.x;
        t = atomicSub(&deg[d.y], 1) - 1; csr[offs[d.y] + t] = s.y;
        t = atomicSub(&deg[d.z], 1) - 1; csr[offs[d.z] + t] = s.z;
        t = atomicSub(&deg[d.w], 1) - 1; csr[offs[d.w] + t] = s.w;
    }
}

// ---------------- Layer 1: gather x (8f fp32, float4/lane, 32 edges/load) ----------------

__global__ __launch_bounds__(512) void k_layer1(
    const float* __restrict__ x, const int* __restrict__ csr,
    const int* __restrict__ offs, const float* __restrict__ deginv,
    const float* __restrict__ w1l, const float* __restrict__ w1r,
    const float* __restrict__ b1,
    const float* __restrict__ g1, const float* __restrict__ bb1,
    const float* __restrict__ m1, const float* __restrict__ v1,
    const float* __restrict__ w2l,
    float* __restrict__ h1, bf16* __restrict__ t2)
{
    __shared__ float s_w1l[8 * 64], s_w1r[8 * 64], s_w2l[64 * 64];
    __shared__ float s_b1[64], s_g[64], s_bb[64], s_m[64], s_rstd[64];
    int tid = threadIdx.x;
    for (int i = tid; i < 8 * 64; i += 512) { s_w1l[i] = w1l[i]; s_w1r[i] = w1r[i]; }
    for (int i = tid; i < 64 * 64; i += 512) s_w2l[i] = w2l[i];
    if (tid < 64) {
        s_b1[tid] = b1[tid]; s_g[tid] = g1[tid]; s_bb[tid] = bb1[tid];
        s_m[tid] = m1[tid];  s_rstd[tid] = rsqrtf(v1[tid] + 1e-5f);
    }
    __syncthreads();
    int lane = tid & 63;
    int node = blockIdx.x * 8 + (tid >> 6);
    if (node >= NNODES) return;

    int start = offs[node];
    int d = offs[node + 1] - start;

    int fh = lane & 1;       // half-row: features 4*fh .. 4*fh+3
    int g  = lane >> 1;      // 32 edge slots
    float ax = 0.f, ay = 0.f, az = 0.f, aw = 0.f;
    const float4* xv = (const float4*)x;
    for (int i = g; i < d; i += 32) {
        int s = csr[start + i];
        float4 w = xv[(size_t)s * 2 + fh];
        ax += w.x; ay += w.y; az += w.z; aw += w.w;
    }
#define RED1(X) X += __shfl_xor(X, 2); X += __shfl_xor(X, 4); X += __shfl_xor(X, 8); \
                X += __shfl_xor(X, 16); X += __shfl_xor(X, 32);
    RED1(ax) RED1(ay) RED1(az) RED1(aw)
#undef RED1
    float di = deginv[node];
    ax *= di; ay *= di; az *= di; aw *= di;

    float xs = x[node * 8 + (lane & 7)];

    float h = s_b1[lane];
#pragma unroll
    for (int k = 0; k < 8; k++) {
        float comp = ((k & 3) == 0) ? ax : ((k & 3) == 1) ? ay : ((k & 3) == 2) ? az : aw;
        float a  = __shfl(comp, k >> 2);
        float xr = __shfl(xs, k);
        h += a * s_w1l[k * 64 + lane] + xr * s_w1r[k * 64 + lane];
    }
    h = (h - s_m[lane]) * s_rstd[lane] * s_g[lane] + s_bb[lane];
    h = fmaxf(h, 0.f);
    h1[node * 64 + lane] = h;

    float t = 0.f;
#pragma unroll
    for (int k = 0; k < 64; k++) {
        float hv = __shfl(h, k);
        t += hv * s_w2l[k * 64 + lane];
    }
    t2[node * 64 + lane] = f2b(t);
}

// ---------------- Layer 2: gather t2 (64f bf16, uint4/lane, 8 edges/load) ----------------

__global__ __launch_bounds__(512) void k_layer2(
    const bf16* __restrict__ t2, const float* __restrict__ h1,
    const int* __restrict__ csr, const int* __restrict__ offs,
    const float* __restrict__ deginv,
    const float* __restrict__ w2r, const float* __restrict__ b2,
    const float* __restrict__ g2, const float* __restrict__ bb2,
    const float* __restrict__ m2, const float* __restrict__ v2,
    const float* __restrict__ w3l,
    float* __restrict__ h2, bf16* __restrict__ t3)
{
    __shared__ float s_w2r[64 * 64], s_w3l[64 * 32];
    __shared__ float s_b[64], s_g[64], s_bb[64], s_m[64], s_rstd[64];
    int tid = threadIdx.x;
    for (int i = tid; i < 64 * 64; i += 512) s_w2r[i] = w2r[i];
    for (int i = tid; i < 64 * 32; i += 512) s_w3l[i] = w3l[i];
    if (tid < 64) {
        s_b[tid] = b2[tid]; s_g[tid] = g2[tid]; s_bb[tid] = bb2[tid];
        s_m[tid] = m2[tid]; s_rstd[tid] = rsqrtf(v2[tid] + 1e-5f);
    }
    __syncthreads();
    int lane = tid & 63;
    int node = blockIdx.x * 8 + (tid >> 6);
    if (node >= NNODES) return;

    int start = offs[node];
    int d = offs[node + 1] - start;

    int fq = lane & 7;       // feature octet: features 8*fq .. 8*fq+7
    int g  = lane >> 3;      // 8 edge slots
    float a0 = 0, a1 = 0, a2 = 0, a3 = 0, a4 = 0, a5 = 0, a6 = 0, a7 = 0;
    const uint4* t2v = (const uint4*)t2;  // row = 8 x uint4

    int i = g;
    for (; i + 8 < d; i += 16) {           // 2-deep: 2 independent dwordx4 in flight
        int s0 = csr[start + i];
        int s1 = csr[start + i + 8];
        uint4 w0 = t2v[(size_t)s0 * 8 + fq];
        uint4 w1 = t2v[(size_t)s1 * 8 + fq];
        a0 += lo2f(w0.x); a1 += hi2f(w0.x); a2 += lo2f(w0.y); a3 += hi2f(w0.y);
        a4 += lo2f(w0.z); a5 += hi2f(w0.z); a6 += lo2f(w0.w); a7 += hi2f(w0.w);
        a0 += lo2f(w1.x); a1 += hi2f(w1.x); a2 += lo2f(w1.y); a3 += hi2f(w1.y);
        a4 += lo2f(w1.z); a5 += hi2f(w1.z); a6 += lo2f(w1.w); a7 += hi2f(w1.w);
    }
    for (; i < d; i += 8) {
        int s = csr[start + i];
        uint4 w = t2v[(size_t)s * 8 + fq];
        a0 += lo2f(w.x); a1 += hi2f(w.x); a2 += lo2f(w.y); a3 += hi2f(w.y);
        a4 += lo2f(w.z); a5 += hi2f(w.z); a6 += lo2f(w.w); a7 += hi2f(w.w);
    }
#define RED2(X) X += __shfl_xor(X, 8); X += __shfl_xor(X, 16); X += __shfl_xor(X, 32);
    RED2(a0) RED2(a1) RED2(a2) RED2(a3) RED2(a4) RED2(a5) RED2(a6) RED2(a7)
#undef RED2
    // lane -> agg[lane]: select comp (lane>>3), then bit-swap bpermute
    float u = sel8(lane >> 3, a0, a1, a2, a3, a4, a5, a6, a7);
    int srcl = ((lane & 7) << 3) | (lane >> 3);
    float v = __shfl(u, srcl);
    v *= deginv[node];

    float h1v = h1[node * 64 + lane];
    float h = v + s_b[lane];
#pragma unroll
    for (int k = 0; k < 64; k++) {
        float hv = __shfl(h1v, k);
        h += hv * s_w2r[k * 64 + lane];
    }
    h = (h - s_m[lane]) * s_rstd[lane] * s_g[lane] + s_bb[lane];
    h = fmaxf(h, 0.f);
    h2[node * 64 + lane] = h;

    int j = lane & 31;
    float t = 0.f;
#pragma unroll
    for (int k = 0; k < 64; k++) {
        float hv = __shfl(h, k);
        t += hv * s_w3l[k * 32 + j];
    }
    if (lane < 32) t3[node * 32 + lane] = f2b(t);
}

// ---------------- Layer 3: gather t3 (32f bf16, uint4/lane, 16 edges/load) ----------------

__global__ __launch_bounds__(512) void k_layer3(
    const bf16* __restrict__ t3, const float* __restrict__ h2,
    const int* __restrict__ csr, const int* __restrict__ offs,
    const float* __restrict__ deginv,
    const float* __restrict__ w3r, const float* __restrict__ b3,
    const float* __restrict__ fcw, const float* __restrict__ fcb,
    float* __restrict__ out)
{
    __shared__ float s_w3r[64 * 32];
    __shared__ float s_b3[32], s_fcw[32];
    __shared__ float s_fcb;
    int tid = threadIdx.x;
    for (int i = tid; i < 64 * 32; i += 512) s_w3r[i] = w3r[i];
    if (tid < 32) { s_b3[tid] = b3[tid]; s_fcw[tid] = fcw[tid]; }
    if (tid == 0) s_fcb = fcb[0];
    __syncthreads();
    int lane = tid & 63;
    int node = blockIdx.x * 8 + (tid >> 6);
    if (node >= NNODES) return;

    int start = offs[node];
    int d = offs[node + 1] - start;

    int fq = lane & 3;       // features 8*fq .. 8*fq+7 (of 32)
    int g  = lane >> 2;      // 16 edge slots
    float a0 = 0, a1 = 0, a2 = 0, a3 = 0, a4 = 0, a5 = 0, a6 = 0, a7 = 0;
    const uint4* t3v = (const uint4*)t3;  // row = 4 x uint4

    int i = g;
    for (; i + 16 < d; i += 32) {
        int s0 = csr[start + i];
        int s1 = csr[start + i + 16];
        uint4 w0 = t3v[(size_t)s0 * 4 + fq];
        uint4 w1 = t3v[(size_t)s1 * 4 + fq];
        a0 += lo2f(w0.x); a1 += hi2f(w0.x); a2 += lo2f(w0.y); a3 += hi2f(w0.y);
        a4 += lo2f(w0.z); a5 += hi2f(w0.z); a6 += lo2f(w0.w); a7 += hi2f(w0.w);
        a0 += lo2f(w1.x); a1 += hi2f(w1.x); a2 += lo2f(w1.y); a3 += hi2f(w1.y);
        a4 += lo2f(w1.z); a5 += hi2f(w1.z); a6 += lo2f(w1.w); a7 += hi2f(w1.w);
    }
    for (; i < d; i += 16) {
        int s = csr[start + i];
        uint4 w = t3v[(size_t)s * 4 + fq];
        a0 += lo2f(w.x); a1 += hi2f(w.x); a2 += lo2f(w.y); a3 += hi2f(w.y);
        a4 += lo2f(w.z); a5 += hi2f(w.z); a6 += lo2f(w.w); a7 += hi2f(w.w);
    }
#define RED3(X) X += __shfl_xor(X, 4); X += __shfl_xor(X, 8); X += __shfl_xor(X, 16); X += __shfl_xor(X, 32);
    RED3(a0) RED3(a1) RED3(a2) RED3(a3) RED3(a4) RED3(a5) RED3(a6) RED3(a7)
#undef RED3
    // lane -> agg[lane&31]
    float u = sel8((lane >> 2) & 7, a0, a1, a2, a3, a4, a5, a6, a7);
    int srcl = ((lane & 7) << 2) | ((lane >> 3) & 3);
    float v = __shfl(u, srcl);
    v *= deginv[node];

    int o = lane & 31;
    float h2v = h2[node * 64 + lane];
    float h = v + s_b3[o];
#pragma unroll
    for (int k = 0; k < 64; k++) {
        float hv = __shfl(h2v, k);
        h += hv * s_w3r[k * 32 + o];
    }
    h = fmaxf(h, 0.f);

    float p = h * s_fcw[o];
    p += __shfl_xor(p, 1);
    p += __shfl_xor(p, 2);
    p += __shfl_xor(p, 4);
    p += __shfl_xor(p, 8);
    p += __shfl_xor(p, 16);
    if (lane == 0) {
        float z = p + s_fcb;
        out[node] = 1.0f / (1.0f + expf(-z));
    }
}

// ---------------- launch ----------------

extern "C" void kernel_launch(void* const* d_in, const int* in_sizes, int n_in,
                              void* d_out, int out_size, void* d_ws, size_t ws_size,
                              hipStream_t stream)
{
    const float* x   = (const float*)d_in[0];
    const int*   ei  = (const int*)d_in[1];
    const int*   src = ei;
    const int*   dst = ei + NEDGES;
    const float* w1l = (const float*)d_in[2];
    const float* w1r = (const float*)d_in[3];
    const float* b1  = (const float*)d_in[4];
    const float* g1  = (const float*)d_in[5];
    const float* bb1 = (const float*)d_in[6];
    const float* m1  = (const float*)d_in[7];
    const float* v1  = (const float*)d_in[8];
    const float* w2l = (const float*)d_in[9];
    const float* w2r = (const float*)d_in[10];
    const float* b2  = (const float*)d_in[11];
    const float* g2  = (const float*)d_in[12];
    const float* bb2 = (const float*)d_in[13];
    const float* m2  = (const float*)d_in[14];
    const float* v2  = (const float*)d_in[15];
    const float* w3l = (const float*)d_in[16];
    const float* w3r = (const float*)d_in[17];
    const float* b3  = (const float*)d_in[18];
    const float* fcw = (const float*)d_in[19];
    const float* fcb = (const float*)d_in[20];

    char* ws = (char*)d_ws;
    size_t off = 0;
    auto alloc = [&](size_t bytes) -> void* {
        void* p = ws + off;
        off += (bytes + 255) & ~(size_t)255;
        return p;
    };
    int*   deg    = (int*)alloc((size_t)NNODES * 4);
    int*   offs   = (int*)alloc((size_t)(NNODES + 1) * 4);
    int*   cs     = (int*)alloc((size_t)NCH * 4);
    int*   co     = (int*)alloc((size_t)NCH * 4);
    float* deginv = (float*)alloc((size_t)NNODES * 4);
    int*   csr    = (int*)alloc((size_t)NEDGES * 4);
    float* h1     = (float*)alloc((size_t)NNODES * 64 * 4);
    bf16*  t2     = (bf16*)alloc((size_t)NNODES * 64 * 2);
    float* h2     = (float*)alloc((size_t)NNODES * 64 * 4);
    bf16*  t3     = (bf16*)alloc((size_t)NNODES * 32 * 2);

    hipMemsetAsync(deg, 0, (size_t)NNODES * 4, stream);

    k_deg<<<(NEDGES / 4 + 255) / 256, 256, 0, stream>>>((const int4*)dst, deg);
    k_chunksum<<<(NCH + 255) / 256, 256, 0, stream>>>(deg, cs);
    k_scan<<<1, 1024, 0, stream>>>(cs, co);
    k_offsets<<<(NCH + 255) / 256, 256, 0, stream>>>(deg, co, offs, deginv);
    k_sentinel<<<1, 64, 0, stream>>>(offs);
    k_fill<<<(NEDGES / 4 + 255) / 256, 256, 0, stream>>>((const int4*)src, (const int4*)dst,
                                                         offs, deg, csr);

    int nb = (NNODES + 7) / 8;
    k_layer1<<<nb, 512, 0, stream>>>(x, csr, offs, deginv,
                                     w1l, w1r, b1, g1, bb1, m1, v1, w2l, h1, t2);
    k_layer2<<<nb, 512, 0, stream>>>(t2, h1, csr, offs, deginv,
                                     w2r, b2, g2, bb2, m2, v2, w3l, h2, t3);
    k_layer3<<<nb, 512, 0, stream>>>(t3, h2, csr, offs, deginv,
                                     w3r, b3, fcw, fcb, (float*)d_out);
}

// Round 4
// 764.493 us; speedup vs baseline: 1.6237x; 1.1801x over previous
//
#include <hip/hip_runtime.h>
#include <hip/hip_bf16.h>
#include <math.h>

#define NNODES 100000
#define NEDGES 3200000
constexpr int CHUNK = 128;
constexpr int NCH = (NNODES + CHUNK - 1) / CHUNK; // 782

typedef __hip_bfloat16 bf16;
__device__ __forceinline__ bf16 f2b(float v) { return __float2bfloat16(v); }
__device__ __forceinline__ float lo2f(unsigned u) { return __uint_as_float(u << 16); }
__device__ __forceinline__ float hi2f(unsigned u) { return __uint_as_float(u & 0xffff0000u); }

// 8-way compile-time-tree select: returns a[c], c in 0..7
__device__ __forceinline__ float sel8(int c, float a0, float a1, float a2, float a3,
                                      float a4, float a5, float a6, float a7) {
    float b0 = (c & 1) ? a1 : a0, b2 = (c & 1) ? a3 : a2;
    float b4 = (c & 1) ? a5 : a4, b6 = (c & 1) ? a7 : a6;
    float c0 = (c & 2) ? b2 : b0, c4 = (c & 2) ? b6 : b4;
    return (c & 4) ? c4 : c0;
}

// ---------------- CSR build ----------------

__global__ void k_deg(const int4* __restrict__ dst4, int* __restrict__ deg) {
    int e = blockIdx.x * blockDim.x + threadIdx.x;
    if (e < NEDGES / 4) {
        int4 d = dst4[e];
        atomicAdd(&deg[d.x], 1);
        atomicAdd(&deg[d.y], 1);
        atomicAdd(&deg[d.z], 1);
        atomicAdd(&deg[d.w], 1);
    }
}

__global__ void k_chunksum(const int* __restrict__ deg, int* __restrict__ cs) {
    int c = blockIdx.x * blockDim.x + threadIdx.x;
    if (c >= NCH) return;
    int base = c * CHUNK, lim = min(CHUNK, NNODES - base), s = 0;
    for (int j = 0; j < lim; j++) s += deg[base + j];
    cs[c] = s;
}

__global__ void k_scan(const int* __restrict__ cs, int* __restrict__ co) {
    __shared__ int s[1024];
    int i = threadIdx.x;
    int v = (i < NCH) ? cs[i] : 0;
    s[i] = v;
    __syncthreads();
    for (int off = 1; off < 1024; off <<= 1) {
        int t = (i >= off) ? s[i - off] : 0;
        __syncthreads();
        s[i] += t;
        __syncthreads();
    }
    if (i < NCH) co[i] = s[i] - v;  // exclusive
}

__global__ void k_offsets(const int* __restrict__ deg, const int* __restrict__ co,
                          int* __restrict__ offs, float* __restrict__ deginv) {
    int c = blockIdx.x * blockDim.x + threadIdx.x;
    if (c >= NCH) return;
    int base = c * CHUNK, lim = min(CHUNK, NNODES - base), run = co[c];
    for (int j = 0; j < lim; j++) {
        int idx = base + j, d = deg[idx];
        offs[idx] = run;
        deginv[idx] = 1.0f / (float)max(d, 1);
        run += d;
    }
}

__global__ void k_sentinel(int* __restrict__ offs) {
    if (threadIdx.x == 0 && blockIdx.x == 0) offs[NNODES] = NEDGES;
}

// consumes deg (atomicSub down to 0)
__global__ void k_fill(const int4* __restrict__ src4, const int4* __restrict__ dst4,
                       const int* __restrict__ offs, int* __restrict__ deg,
                       int* __restrict__ csr) {
    int e = blockIdx.x * blockDim.x + threadIdx.x;
    if (e < NEDGES / 4) {
        int4 s = src4[e];
        int4 d = dst4[e];
        int t;
        t = atomicSub(&deg[d.x], 1) - 1; csr[offs[d.x] + t] = s.x;
        t = atomicSub(&deg[d.y], 1) - 1; csr[offs[d.y] + t] = s.y;
        t = atomicSub(&deg[d.z], 1) - 1; csr[offs[d.z] + t] = s.z;
        t = atomicSub(&deg[d.w], 1) - 1; csr[offs[d.w] + t] = s.w;
    }
}

// ---- Layer 1: gather x (8f fp32) -> h1 (regs) -> t2 = h1@(w2l*k2) bf16, r2 = h1@(w2r*k2)+c2 ----
// BN1 folded into w1l/w1r/c1; BN2 folded into w2l/w2r/c2r.

__global__ __launch_bounds__(512) void k_layer1(
    const float* __restrict__ x, const int* __restrict__ csr,
    const int* __restrict__ offs, const float* __restrict__ deginv,
    const float* __restrict__ w1l, const float* __restrict__ w1r,
    const float* __restrict__ b1,
    const float* __restrict__ g1, const float* __restrict__ bb1,
    const float* __restrict__ m1, const float* __restrict__ v1,
    const float* __restrict__ w2l, const float* __restrict__ w2r,
    const float* __restrict__ b2,
    const float* __restrict__ g2, const float* __restrict__ bb2,
    const float* __restrict__ m2, const float* __restrict__ v2,
    bf16* __restrict__ t2, float* __restrict__ r2)
{
    __shared__ float s_w1l[8 * 64], s_w1r[8 * 64];
    __shared__ float s_w2l[64 * 64], s_w2r[64 * 64];
    __shared__ float s_c1[64], s_c2[64];
    int tid = threadIdx.x;
    // BN fold scales
    for (int i = tid; i < 8 * 64; i += 512) {
        int col = i & 63;
        float k1 = g1[col] * rsqrtf(v1[col] + 1e-5f);
        s_w1l[i] = w1l[i] * k1;
        s_w1r[i] = w1r[i] * k1;
    }
    for (int i = tid; i < 64 * 64; i += 512) {
        int col = i & 63;
        float k2 = g2[col] * rsqrtf(v2[col] + 1e-5f);
        s_w2l[i] = w2l[i] * k2;
        s_w2r[i] = w2r[i] * k2;
    }
    if (tid < 64) {
        float k1 = g1[tid] * rsqrtf(v1[tid] + 1e-5f);
        float k2 = g2[tid] * rsqrtf(v2[tid] + 1e-5f);
        s_c1[tid] = (b1[tid] - m1[tid]) * k1 + bb1[tid];
        s_c2[tid] = (b2[tid] - m2[tid]) * k2 + bb2[tid];
    }
    __syncthreads();
    int lane = tid & 63;
    int node = blockIdx.x * 8 + (tid >> 6);
    if (node >= NNODES) return;

    int start = offs[node];
    int d = offs[node + 1] - start;
    int dl = min(d, 64);
    int c = csr[start + lane];                 // csr padded +64
    float xs = x[node * 8 + (lane & 7)];

    int fh = lane & 1;       // half-row: features 4*fh..4*fh+3
    int g  = lane >> 1;      // 32 edge slots, stride 32
    const float4* xv = (const float4*)x;

    int i0 = g,      i1 = g + 32;
    int s0 = __shfl(c, i0), s1 = __shfl(c, i1);
    float m0 = (i0 < dl) ? 1.f : 0.f;
    float m1f = (i1 < dl) ? 1.f : 0.f;
    s0 = (i0 < dl) ? s0 : 0;
    s1 = (i1 < dl) ? s1 : 0;
    float4 w0 = xv[(size_t)s0 * 2 + fh];
    float4 w1 = xv[(size_t)s1 * 2 + fh];
    float ax = m0 * w0.x + m1f * w1.x;
    float ay = m0 * w0.y + m1f * w1.y;
    float az = m0 * w0.z + m1f * w1.z;
    float aw = m0 * w0.w + m1f * w1.w;
    for (int i = g + 64; i < d; i += 32) {     // rare tail
        int s = csr[start + i];
        float4 w = xv[(size_t)s * 2 + fh];
        ax += w.x; ay += w.y; az += w.z; aw += w.w;
    }
#define RED1(X) X += __shfl_xor(X, 2); X += __shfl_xor(X, 4); X += __shfl_xor(X, 8); \
                X += __shfl_xor(X, 16); X += __shfl_xor(X, 32);
    RED1(ax) RED1(ay) RED1(az) RED1(aw)
#undef RED1
    float di = deginv[node];
    ax *= di; ay *= di; az *= di; aw *= di;

    float h = s_c1[lane];
#pragma unroll
    for (int k = 0; k < 8; k++) {
        float comp = ((k & 3) == 0) ? ax : ((k & 3) == 1) ? ay : ((k & 3) == 2) ? az : aw;
        float a  = __shfl(comp, k >> 2);
        float xr = __shfl(xs, k);
        h += a * s_w1l[k * 64 + lane] + xr * s_w1r[k * 64 + lane];
    }
    h = fmaxf(h, 0.f);   // h1 in regs only

    float tt = 0.f, rr = s_c2[lane];
#pragma unroll
    for (int k = 0; k < 64; k++) {
        float hv = __shfl(h, k);
        tt += hv * s_w2l[k * 64 + lane];
        rr += hv * s_w2r[k * 64 + lane];
    }
    t2[(size_t)node * 64 + lane] = f2b(tt);
    r2[(size_t)node * 64 + lane] = rr;
}

// ---- Layer 2: gather t2 (bf16, 8 gathers in flight) -> h2 regs -> t3 = h2@w3l bf16, r3 = h2@w3r+b3 ----

__global__ __launch_bounds__(256) void k_layer2(
    const bf16* __restrict__ t2, const float* __restrict__ r2,
    const int* __restrict__ csr, const int* __restrict__ offs,
    const float* __restrict__ deginv,
    const float* __restrict__ w3l, const float* __restrict__ w3r,
    const float* __restrict__ b3,
    bf16* __restrict__ t3, float* __restrict__ r3)
{
    __shared__ float s_w3l[64 * 32], s_w3r[64 * 32];
    __shared__ float s_b3[32];
    int tid = threadIdx.x;
    for (int i = tid; i < 64 * 32; i += 256) { s_w3l[i] = w3l[i]; s_w3r[i] = w3r[i]; }
    if (tid < 32) s_b3[tid] = b3[tid];
    __syncthreads();
    int lane = tid & 63;
    int node = blockIdx.x * 4 + (tid >> 6);
    if (node >= NNODES) return;

    int start = offs[node];
    int d = offs[node + 1] - start;
    int dl = min(d, 64);
    int c = csr[start + lane];                        // coalesced, padded
    float r2v = r2[(size_t)node * 64 + lane];         // early independent load

    int fq = lane & 7;       // feature octet
    int g  = lane >> 3;      // 8 edge slots, stride 8
    const uint4* t2v = (const uint4*)t2;

    // 8 unpredicated clamped-index gathers -> max MLP
    int   si[8];
    float mk[8];
#pragma unroll
    for (int t = 0; t < 8; t++) {
        int i = g + 8 * t;
        int s = __shfl(c, i);
        mk[t] = (i < dl) ? 1.f : 0.f;
        si[t] = (i < dl) ? s : 0;
    }
    uint4 w0 = t2v[(size_t)si[0] * 8 + fq];
    uint4 w1 = t2v[(size_t)si[1] * 8 + fq];
    uint4 w2 = t2v[(size_t)si[2] * 8 + fq];
    uint4 w3 = t2v[(size_t)si[3] * 8 + fq];
    uint4 w4 = t2v[(size_t)si[4] * 8 + fq];
    uint4 w5 = t2v[(size_t)si[5] * 8 + fq];
    uint4 w6 = t2v[(size_t)si[6] * 8 + fq];
    uint4 w7 = t2v[(size_t)si[7] * 8 + fq];

    float a0 = 0, a1 = 0, a2 = 0, a3 = 0, a4 = 0, a5 = 0, a6 = 0, a7 = 0;
#define CONS(W, M) \
    a0 = fmaf(M, lo2f(W.x), a0); a1 = fmaf(M, hi2f(W.x), a1); \
    a2 = fmaf(M, lo2f(W.y), a2); a3 = fmaf(M, hi2f(W.y), a3); \
    a4 = fmaf(M, lo2f(W.z), a4); a5 = fmaf(M, hi2f(W.z), a5); \
    a6 = fmaf(M, lo2f(W.w), a6); a7 = fmaf(M, hi2f(W.w), a7);
    CONS(w0, mk[0]) CONS(w1, mk[1]) CONS(w2, mk[2]) CONS(w3, mk[3])
    CONS(w4, mk[4]) CONS(w5, mk[5]) CONS(w6, mk[6]) CONS(w7, mk[7])
    for (int i = g + 64; i < d; i += 8) {             // rare tail
        int s = csr[start + i];
        uint4 w = t2v[(size_t)s * 8 + fq];
        CONS(w, 1.f)
    }
#undef CONS
#define RED2(X) X += __shfl_xor(X, 8); X += __shfl_xor(X, 16); X += __shfl_xor(X, 32);
    RED2(a0) RED2(a1) RED2(a2) RED2(a3) RED2(a4) RED2(a5) RED2(a6) RED2(a7)
#undef RED2
    float u = sel8(lane >> 3, a0, a1, a2, a3, a4, a5, a6, a7);
    int srcl = ((lane & 7) << 3) | (lane >> 3);
    float v = __shfl(u, srcl);

    float h2 = fmaxf(v * deginv[node] + r2v, 0.f);    // BN folded upstream

    int j = lane & 31;
    float tt = 0.f, rr = s_b3[j];
#pragma unroll
    for (int k = 0; k < 64; k++) {
        float hv = __shfl(h2, k);
        tt += hv * s_w3l[k * 32 + j];
        rr += hv * s_w3r[k * 32 + j];
    }
    if (lane < 32) {
        t3[(size_t)node * 32 + j] = f2b(tt);
        r3[(size_t)node * 32 + j] = rr;
    }
}

// ---- Layer 3: gather t3 (bf16, 4 gathers in flight) -> relu(agg+r3) -> fc -> sigmoid ----

__global__ __launch_bounds__(256) void k_layer3(
    const bf16* __restrict__ t3, const float* __restrict__ r3,
    const int* __restrict__ csr, const int* __restrict__ offs,
    const float* __restrict__ deginv,
    const float* __restrict__ fcw, const float* __restrict__ fcb,
    float* __restrict__ out)
{
    __shared__ float s_fcw[32];
    __shared__ float s_fcb;
    int tid = threadIdx.x;
    if (tid < 32) s_fcw[tid] = fcw[tid];
    if (tid == 0) s_fcb = fcb[0];
    __syncthreads();
    int lane = tid & 63;
    int node = blockIdx.x * 4 + (tid >> 6);
    if (node >= NNODES) return;

    int o = lane & 31;
    int start = offs[node];
    int d = offs[node + 1] - start;
    int dl = min(d, 64);
    int c = csr[start + lane];
    float r3v = r3[(size_t)node * 32 + o];            // early

    int fq = lane & 3;       // feature octet of 32
    int g  = lane >> 2;      // 16 edge slots, stride 16
    const uint4* t3v = (const uint4*)t3;

    int   si[4];
    float mk[4];
#pragma unroll
    for (int t = 0; t < 4; t++) {
        int i = g + 16 * t;
        int s = __shfl(c, i);
        mk[t] = (i < dl) ? 1.f : 0.f;
        si[t] = (i < dl) ? s : 0;
    }
    uint4 w0 = t3v[(size_t)si[0] * 4 + fq];
    uint4 w1 = t3v[(size_t)si[1] * 4 + fq];
    uint4 w2 = t3v[(size_t)si[2] * 4 + fq];
    uint4 w3 = t3v[(size_t)si[3] * 4 + fq];

    float a0 = 0, a1 = 0, a2 = 0, a3 = 0, a4 = 0, a5 = 0, a6 = 0, a7 = 0;
#define CONS(W, M) \
    a0 = fmaf(M, lo2f(W.x), a0); a1 = fmaf(M, hi2f(W.x), a1); \
    a2 = fmaf(M, lo2f(W.y), a2); a3 = fmaf(M, hi2f(W.y), a3); \
    a4 = fmaf(M, lo2f(W.z), a4); a5 = fmaf(M, hi2f(W.z), a5); \
    a6 = fmaf(M, lo2f(W.w), a6); a7 = fmaf(M, hi2f(W.w), a7);
    CONS(w0, mk[0]) CONS(w1, mk[1]) CONS(w2, mk[2]) CONS(w3, mk[3])
    for (int i = g + 64; i < d; i += 16) {            // rare tail
        int s = csr[start + i];
        uint4 w = t3v[(size_t)s * 4 + fq];
        CONS(w, 1.f)
    }
#undef CONS
#define RED3(X) X += __shfl_xor(X, 4); X += __shfl_xor(X, 8); X += __shfl_xor(X, 16); X += __shfl_xor(X, 32);
    RED3(a0) RED3(a1) RED3(a2) RED3(a3) RED3(a4) RED3(a5) RED3(a6) RED3(a7)
#undef RED3
    float u = sel8((lane >> 2) & 7, a0, a1, a2, a3, a4, a5, a6, a7);
    int srcl = ((lane & 7) << 2) | ((lane >> 3) & 3);
    float v = __shfl(u, srcl);

    float h3 = fmaxf(v * deginv[node] + r3v, 0.f);

    float p = h3 * s_fcw[o];
    p += __shfl_xor(p, 1);
    p += __shfl_xor(p, 2);
    p += __shfl_xor(p, 4);
    p += __shfl_xor(p, 8);
    p += __shfl_xor(p, 16);
    if (lane == 0) {
        float z = p + s_fcb;
        out[node] = 1.0f / (1.0f + expf(-z));
    }
}

// ---------------- launch ----------------

extern "C" void kernel_launch(void* const* d_in, const int* in_sizes, int n_in,
                              void* d_out, int out_size, void* d_ws, size_t ws_size,
                              hipStream_t stream)
{
    const float* x   = (const float*)d_in[0];
    const int*   ei  = (const int*)d_in[1];
    const int*   src = ei;
    const int*   dst = ei + NEDGES;
    const float* w1l = (const float*)d_in[2];
    const float* w1r = (const float*)d_in[3];
    const float* b1  = (const float*)d_in[4];
    const float* g1  = (const float*)d_in[5];
    const float* bb1 = (const float*)d_in[6];
    const float* m1  = (const float*)d_in[7];
    const float* v1  = (const float*)d_in[8];
    const float* w2l = (const float*)d_in[9];
    const float* w2r = (const float*)d_in[10];
    const float* b2  = (const float*)d_in[11];
    const float* g2  = (const float*)d_in[12];
    const float* bb2 = (const float*)d_in[13];
    const float* m2  = (const float*)d_in[14];
    const float* v2  = (const float*)d_in[15];
    const float* w3l = (const float*)d_in[16];
    const float* w3r = (const float*)d_in[17];
    const float* b3  = (const float*)d_in[18];
    const float* fcw = (const float*)d_in[19];
    const float* fcb = (const float*)d_in[20];

    char* ws = (char*)d_ws;
    size_t off = 0;
    auto alloc = [&](size_t bytes) -> void* {
        void* p = ws + off;
        off += (bytes + 255) & ~(size_t)255;
        return p;
    };
    int*   deg    = (int*)alloc((size_t)NNODES * 4);
    int*   offs   = (int*)alloc((size_t)(NNODES + 1) * 4);
    int*   cs     = (int*)alloc((size_t)NCH * 4);
    int*   co     = (int*)alloc((size_t)NCH * 4);
    float* deginv = (float*)alloc((size_t)NNODES * 4);
    int*   csr    = (int*)alloc((size_t)(NEDGES + 64) * 4);  // +64 pad for coalesced c load
    bf16*  t2     = (bf16*)alloc((size_t)NNODES * 64 * 2);
    float* r2     = (float*)alloc((size_t)NNODES * 64 * 4);
    bf16*  t3     = (bf16*)alloc((size_t)NNODES * 32 * 2);
    float* r3     = (float*)alloc((size_t)NNODES * 32 * 4);

    hipMemsetAsync(deg, 0, (size_t)NNODES * 4, stream);

    k_deg<<<(NEDGES / 4 + 255) / 256, 256, 0, stream>>>((const int4*)dst, deg);
    k_chunksum<<<(NCH + 255) / 256, 256, 0, stream>>>(deg, cs);
    k_scan<<<1, 1024, 0, stream>>>(cs, co);
    k_offsets<<<(NCH + 255) / 256, 256, 0, stream>>>(deg, co, offs, deginv);
    k_sentinel<<<1, 64, 0, stream>>>(offs);
    k_fill<<<(NEDGES / 4 + 255) / 256, 256, 0, stream>>>((const int4*)src, (const int4*)dst,
                                                         offs, deg, csr);

    k_layer1<<<(NNODES + 7) / 8, 512, 0, stream>>>(x, csr, offs, deginv,
                                                   w1l, w1r, b1, g1, bb1, m1, v1,
                                                   w2l, w2r, b2, g2, bb2, m2, v2,
                                                   t2, r2);
    k_layer2<<<(NNODES + 3) / 4, 256, 0, stream>>>(t2, r2, csr, offs, deginv,
                                                   w3l, w3r, b3, t3, r3);
    k_layer3<<<(NNODES + 3) / 4, 256, 0, stream>>>(t3, r3, csr, offs, deginv,
                                                   fcw, fcb, (float*)d_out);
}

// Round 5
// 678.264 us; speedup vs baseline: 1.8301x; 1.1271x over previous
//
#include <hip/hip_runtime.h>
#include <hip/hip_bf16.h>
#include <math.h>

#define NNODES 100000
#define NEDGES 3200000
constexpr int NCHB = (NNODES + 255) / 256; // 391 blocks of 256 nodes

typedef __hip_bfloat16 bf16;
__device__ __forceinline__ bf16 f2b(float v) { return __float2bfloat16(v); }
__device__ __forceinline__ float lo2f(unsigned u) { return __uint_as_float(u << 16); }
__device__ __forceinline__ float hi2f(unsigned u) { return __uint_as_float(u & 0xffff0000u); }

// 8-way compile-time-tree select: returns a[c], c in 0..7
__device__ __forceinline__ float sel8(int c, float a0, float a1, float a2, float a3,
                                      float a4, float a5, float a6, float a7) {
    float b0 = (c & 1) ? a1 : a0, b2 = (c & 1) ? a3 : a2;
    float b4 = (c & 1) ? a5 : a4, b6 = (c & 1) ? a7 : a6;
    float c0 = (c & 2) ? b2 : b0, c4 = (c & 2) ? b6 : b4;
    return (c & 4) ? c4 : c0;
}

// ---------------- CSR build ----------------

__global__ void k_deg(const int4* __restrict__ dst4, int* __restrict__ deg) {
    int e = blockIdx.x * blockDim.x + threadIdx.x;
    if (e < NEDGES / 4) {
        int4 d = dst4[e];
        atomicAdd(&deg[d.x], 1);
        atomicAdd(&deg[d.y], 1);
        atomicAdd(&deg[d.z], 1);
        atomicAdd(&deg[d.w], 1);
    }
}

// per-256-node block sums
__global__ __launch_bounds__(256) void k_blocksum(const int* __restrict__ deg,
                                                  int* __restrict__ bs) {
    int tid = threadIdx.x;
    int node = blockIdx.x * 256 + tid;
    int v = (node < NNODES) ? deg[node] : 0;
    v += __shfl_xor(v, 1);  v += __shfl_xor(v, 2);  v += __shfl_xor(v, 4);
    v += __shfl_xor(v, 8);  v += __shfl_xor(v, 16); v += __shfl_xor(v, 32);
    __shared__ int ws[4];
    if ((tid & 63) == 0) ws[tid >> 6] = v;
    __syncthreads();
    if (tid == 0) bs[blockIdx.x] = ws[0] + ws[1] + ws[2] + ws[3];
}

// exclusive scan of the 391 block sums (single block), + sentinel
__global__ void k_scanbs(const int* __restrict__ bs, int* __restrict__ bse,
                         int* __restrict__ offs) {
    __shared__ int s[512];
    int i = threadIdx.x;
    int v = (i < NCHB) ? bs[i] : 0;
    s[i] = v;
    __syncthreads();
    for (int off = 1; off < 512; off <<= 1) {
        int t = (i >= off) ? s[i - off] : 0;
        __syncthreads();
        s[i] += t;
        __syncthreads();
    }
    if (i < NCHB) bse[i] = s[i] - v;  // exclusive
    if (i == 0) offs[NNODES] = NEDGES;
}

// per-node offsets via wave scan + block scan
__global__ __launch_bounds__(256) void k_offsets(const int* __restrict__ deg,
                                                 const int* __restrict__ bse,
                                                 int* __restrict__ offs,
                                                 float* __restrict__ deginv) {
    int tid = threadIdx.x;
    int lane = tid & 63, wid = tid >> 6;
    int node = blockIdx.x * 256 + tid;
    int d = (node < NNODES) ? deg[node] : 0;
    int v = d;  // inclusive wave scan
    { int t = __shfl_up(v, 1);  if (lane >= 1)  v += t; }
    { int t = __shfl_up(v, 2);  if (lane >= 2)  v += t; }
    { int t = __shfl_up(v, 4);  if (lane >= 4)  v += t; }
    { int t = __shfl_up(v, 8);  if (lane >= 8)  v += t; }
    { int t = __shfl_up(v, 16); if (lane >= 16) v += t; }
    { int t = __shfl_up(v, 32); if (lane >= 32) v += t; }
    __shared__ int ws[4];
    if (lane == 63) ws[wid] = v;
    __syncthreads();
    int woff = 0;
    for (int i = 0; i < 4; i++) woff += (i < wid) ? ws[i] : 0;
    if (node < NNODES) {
        offs[node] = bse[blockIdx.x] + woff + v - d;
        deginv[node] = 1.0f / (float)max(d, 1);
    }
}

// consumes deg (atomicSub down to 0)
__global__ void k_fill(const int4* __restrict__ src4, const int4* __restrict__ dst4,
                       const int* __restrict__ offs, int* __restrict__ deg,
                       int* __restrict__ csr) {
    int e = blockIdx.x * blockDim.x + threadIdx.x;
    if (e < NEDGES / 4) {
        int4 s = src4[e];
        int4 d = dst4[e];
        int t;
        t = atomicSub(&deg[d.x], 1) - 1; csr[offs[d.x] + t] = s.x;
        t = atomicSub(&deg[d.y], 1) - 1; csr[offs[d.y] + t] = s.y;
        t = atomicSub(&deg[d.z], 1) - 1; csr[offs[d.z] + t] = s.z;
        t = atomicSub(&deg[d.w], 1) - 1; csr[offs[d.w] + t] = s.w;
    }
}

// ---- Layer 1 (persistent, weights in VGPRs): gather x -> h1 regs -> t2 bf16, r2 fp32 ----
// BN1 folded into w1 cols / c1; BN2 folded into w2 cols / c2.

__global__ __launch_bounds__(256) void k_layer1(
    const float* __restrict__ x, const int* __restrict__ csr,
    const int* __restrict__ offs, const float* __restrict__ deginv,
    const float* __restrict__ w1l, const float* __restrict__ w1r,
    const float* __restrict__ b1,
    const float* __restrict__ g1, const float* __restrict__ bb1,
    const float* __restrict__ m1, const float* __restrict__ v1,
    const float* __restrict__ w2l, const float* __restrict__ w2r,
    const float* __restrict__ b2,
    const float* __restrict__ g2, const float* __restrict__ bb2,
    const float* __restrict__ m2, const float* __restrict__ v2,
    bf16* __restrict__ t2, float* __restrict__ r2)
{
    int tid = threadIdx.x;
    int lane = tid & 63, wid = tid >> 6;

    // per-lane (= output column) folded weights in registers
    float k1 = g1[lane] * rsqrtf(v1[lane] + 1e-5f);
    float k2 = g2[lane] * rsqrtf(v2[lane] + 1e-5f);
    float c1 = (b1[lane] - m1[lane]) * k1 + bb1[lane];
    float c2 = (b2[lane] - m2[lane]) * k2 + bb2[lane];
    float w1lr[8], w1rr[8];
#pragma unroll
    for (int k = 0; k < 8; k++) {
        w1lr[k] = w1l[k * 64 + lane] * k1;
        w1rr[k] = w1r[k * 64 + lane] * k1;
    }
    float w2lr[64], w2rr[64];
#pragma unroll
    for (int k = 0; k < 64; k++) {
        w2lr[k] = w2l[k * 64 + lane] * k2;
        w2rr[k] = w2r[k * 64 + lane] * k2;
    }

    const float4* xv = (const float4*)x;
    for (int base = blockIdx.x * 4; base < NNODES; base += gridDim.x * 4) {
        int node = base + wid;
        if (node >= NNODES) continue;

        int start = offs[node];
        int d = offs[node + 1] - start;
        int dl = min(d, 64);
        int c = csr[start + lane];                 // csr padded +64
        float xs = x[node * 8 + (lane & 7)];

        int fh = lane & 1;       // half-row: features 4*fh..4*fh+3
        int g  = lane >> 1;      // 32 edge slots
        int i0 = g, i1 = g + 32;
        int s0 = __shfl(c, i0), s1 = __shfl(c, i1);
        float m0 = (i0 < dl) ? 1.f : 0.f;
        float m1f = (i1 < dl) ? 1.f : 0.f;
        s0 = (i0 < dl) ? s0 : 0;
        s1 = (i1 < dl) ? s1 : 0;
        float4 w0 = xv[(size_t)s0 * 2 + fh];
        float4 w1 = xv[(size_t)s1 * 2 + fh];
        float ax = m0 * w0.x + m1f * w1.x;
        float ay = m0 * w0.y + m1f * w1.y;
        float az = m0 * w0.z + m1f * w1.z;
        float aw = m0 * w0.w + m1f * w1.w;
        for (int i = g + 64; i < d; i += 32) {     // rare tail
            int s = csr[start + i];
            float4 w = xv[(size_t)s * 2 + fh];
            ax += w.x; ay += w.y; az += w.z; aw += w.w;
        }
#define RED1(X) X += __shfl_xor(X, 2); X += __shfl_xor(X, 4); X += __shfl_xor(X, 8); \
                X += __shfl_xor(X, 16); X += __shfl_xor(X, 32);
        RED1(ax) RED1(ay) RED1(az) RED1(aw)
#undef RED1
        float di = deginv[node];
        ax *= di; ay *= di; az *= di; aw *= di;

        float h = c1;
#pragma unroll
        for (int k = 0; k < 8; k++) {
            float comp = ((k & 3) == 0) ? ax : ((k & 3) == 1) ? ay : ((k & 3) == 2) ? az : aw;
            float a  = __shfl(comp, k >> 2);
            float xr = __shfl(xs, k);
            h = fmaf(a, w1lr[k], fmaf(xr, w1rr[k], h));
        }
        h = fmaxf(h, 0.f);   // h1 lives in regs only

        float tt = 0.f, rr = c2;
#pragma unroll
        for (int k = 0; k < 64; k++) {
            float hv = __shfl(h, k);      // compile-time lane -> v_readlane
            tt = fmaf(hv, w2lr[k], tt);
            rr = fmaf(hv, w2rr[k], rr);
        }
        t2[(size_t)node * 64 + lane] = f2b(tt);
        r2[(size_t)node * 64 + lane] = rr;
    }
}

// ---- Layer 2 (persistent, w3 cols in VGPRs): gather t2 -> h2 regs -> t3 bf16, r3 fp32 ----

__global__ __launch_bounds__(256) void k_layer2(
    const bf16* __restrict__ t2, const float* __restrict__ r2,
    const int* __restrict__ csr, const int* __restrict__ offs,
    const float* __restrict__ deginv,
    const float* __restrict__ w3l, const float* __restrict__ w3r,
    const float* __restrict__ b3,
    bf16* __restrict__ t3, float* __restrict__ r3)
{
    int tid = threadIdx.x;
    int lane = tid & 63, wid = tid >> 6;
    int j = lane & 31, half = lane >> 5;

    // lanes 0-31 own w3l column j; lanes 32-63 own w3r column j
    const float* wp = half ? w3r : w3l;
    float wcol[64];
#pragma unroll
    for (int k = 0; k < 64; k++) wcol[k] = wp[k * 32 + j];
    float b3v = half ? b3[j] : 0.f;

    const uint4* t2v = (const uint4*)t2;
    for (int base = blockIdx.x * 4; base < NNODES; base += gridDim.x * 4) {
        int node = base + wid;
        if (node >= NNODES) continue;

        int start = offs[node];
        int d = offs[node + 1] - start;
        int dl = min(d, 64);
        int c = csr[start + lane];
        float r2v = r2[(size_t)node * 64 + lane];   // early independent load

        int fq = lane & 7;       // feature octet
        int g  = lane >> 3;      // 8 edge slots
        int   si[8];
        float mk[8];
#pragma unroll
        for (int t = 0; t < 8; t++) {
            int i = g + 8 * t;
            int s = __shfl(c, i);
            mk[t] = (i < dl) ? 1.f : 0.f;
            si[t] = (i < dl) ? s : 0;
        }
        uint4 w0 = t2v[(size_t)si[0] * 8 + fq];
        uint4 w1 = t2v[(size_t)si[1] * 8 + fq];
        uint4 w2 = t2v[(size_t)si[2] * 8 + fq];
        uint4 w3 = t2v[(size_t)si[3] * 8 + fq];
        uint4 w4 = t2v[(size_t)si[4] * 8 + fq];
        uint4 w5 = t2v[(size_t)si[5] * 8 + fq];
        uint4 w6 = t2v[(size_t)si[6] * 8 + fq];
        uint4 w7 = t2v[(size_t)si[7] * 8 + fq];

        float a0 = 0, a1 = 0, a2 = 0, a3 = 0, a4 = 0, a5 = 0, a6 = 0, a7 = 0;
#define CONS(W, M) \
        a0 = fmaf(M, lo2f(W.x), a0); a1 = fmaf(M, hi2f(W.x), a1); \
        a2 = fmaf(M, lo2f(W.y), a2); a3 = fmaf(M, hi2f(W.y), a3); \
        a4 = fmaf(M, lo2f(W.z), a4); a5 = fmaf(M, hi2f(W.z), a5); \
        a6 = fmaf(M, lo2f(W.w), a6); a7 = fmaf(M, hi2f(W.w), a7);
        CONS(w0, mk[0]) CONS(w1, mk[1]) CONS(w2, mk[2]) CONS(w3, mk[3])
        CONS(w4, mk[4]) CONS(w5, mk[5]) CONS(w6, mk[6]) CONS(w7, mk[7])
        for (int i = g + 64; i < d; i += 8) {       // rare tail
            int s = csr[start + i];
            uint4 w = t2v[(size_t)s * 8 + fq];
            CONS(w, 1.f)
        }
#undef CONS
#define RED2(X) X += __shfl_xor(X, 8); X += __shfl_xor(X, 16); X += __shfl_xor(X, 32);
        RED2(a0) RED2(a1) RED2(a2) RED2(a3) RED2(a4) RED2(a5) RED2(a6) RED2(a7)
#undef RED2
        float u = sel8(lane >> 3, a0, a1, a2, a3, a4, a5, a6, a7);
        int srcl = ((lane & 7) << 3) | (lane >> 3);
        float v = __shfl(u, srcl);

        float h2 = fmaxf(v * deginv[node] + r2v, 0.f);

        float acc = b3v;
#pragma unroll
        for (int k = 0; k < 64; k++) {
            float hv = __shfl(h2, k);
            acc = fmaf(hv, wcol[k], acc);
        }
        if (half == 0) t3[(size_t)node * 32 + j] = f2b(acc);
        else           r3[(size_t)node * 32 + j] = acc;
    }
}

// ---- Layer 3: gather t3 (bf16) -> relu(agg+r3) -> fc -> sigmoid ----

__global__ __launch_bounds__(256) void k_layer3(
    const bf16* __restrict__ t3, const float* __restrict__ r3,
    const int* __restrict__ csr, const int* __restrict__ offs,
    const float* __restrict__ deginv,
    const float* __restrict__ fcw, const float* __restrict__ fcb,
    float* __restrict__ out)
{
    int tid = threadIdx.x;
    int lane = tid & 63;
    int node = blockIdx.x * 4 + (tid >> 6);
    if (node >= NNODES) return;

    int o = lane & 31;
    float fcwv = fcw[o];
    float fcbv = fcb[0];

    int start = offs[node];
    int d = offs[node + 1] - start;
    int dl = min(d, 64);
    int c = csr[start + lane];
    float r3v = r3[(size_t)node * 32 + o];          // early

    int fq = lane & 3;       // feature octet of 32
    int g  = lane >> 2;      // 16 edge slots
    const uint4* t3v = (const uint4*)t3;

    int   si[4];
    float mk[4];
#pragma unroll
    for (int t = 0; t < 4; t++) {
        int i = g + 16 * t;
        int s = __shfl(c, i);
        mk[t] = (i < dl) ? 1.f : 0.f;
        si[t] = (i < dl) ? s : 0;
    }
    uint4 w0 = t3v[(size_t)si[0] * 4 + fq];
    uint4 w1 = t3v[(size_t)si[1] * 4 + fq];
    uint4 w2 = t3v[(size_t)si[2] * 4 + fq];
    uint4 w3 = t3v[(size_t)si[3] * 4 + fq];

    float a0 = 0, a1 = 0, a2 = 0, a3 = 0, a4 = 0, a5 = 0, a6 = 0, a7 = 0;
#define CONS(W, M) \
    a0 = fmaf(M, lo2f(W.x), a0); a1 = fmaf(M, hi2f(W.x), a1); \
    a2 = fmaf(M, lo2f(W.y), a2); a3 = fmaf(M, hi2f(W.y), a3); \
    a4 = fmaf(M, lo2f(W.z), a4); a5 = fmaf(M, hi2f(W.z), a5); \
    a6 = fmaf(M, lo2f(W.w), a6); a7 = fmaf(M, hi2f(W.w), a7);
    CONS(w0, mk[0]) CONS(w1, mk[1]) CONS(w2, mk[2]) CONS(w3, mk[3])
    for (int i = g + 64; i < d; i += 16) {          // rare tail
        int s = csr[start + i];
        uint4 w = t3v[(size_t)s * 4 + fq];
        CONS(w, 1.f)
    }
#undef CONS
#define RED3(X) X += __shfl_xor(X, 4); X += __shfl_xor(X, 8); X += __shfl_xor(X, 16); X += __shfl_xor(X, 32);
    RED3(a0) RED3(a1) RED3(a2) RED3(a3) RED3(a4) RED3(a5) RED3(a6) RED3(a7)
#undef RED3
    float u = sel8((lane >> 2) & 7, a0, a1, a2, a3, a4, a5, a6, a7);
    int srcl = ((lane & 7) << 2) | ((lane >> 3) & 3);
    float v = __shfl(u, srcl);

    float h3 = fmaxf(v * deginv[node] + r3v, 0.f);

    float p = h3 * fcwv;
    p += __shfl_xor(p, 1);
    p += __shfl_xor(p, 2);
    p += __shfl_xor(p, 4);
    p += __shfl_xor(p, 8);
    p += __shfl_xor(p, 16);
    if (lane == 0) {
        float z = p + fcbv;
        out[node] = 1.0f / (1.0f + expf(-z));
    }
}

// ---------------- launch ----------------

extern "C" void kernel_launch(void* const* d_in, const int* in_sizes, int n_in,
                              void* d_out, int out_size, void* d_ws, size_t ws_size,
                              hipStream_t stream)
{
    const float* x   = (const float*)d_in[0];
    const int*   ei  = (const int*)d_in[1];
    const int*   src = ei;
    const int*   dst = ei + NEDGES;
    const float* w1l = (const float*)d_in[2];
    const float* w1r = (const float*)d_in[3];
    const float* b1  = (const float*)d_in[4];
    const float* g1  = (const float*)d_in[5];
    const float* bb1 = (const float*)d_in[6];
    const float* m1  = (const float*)d_in[7];
    const float* v1  = (const float*)d_in[8];
    const float* w2l = (const float*)d_in[9];
    const float* w2r = (const float*)d_in[10];
    const float* b2  = (const float*)d_in[11];
    const float* g2  = (const float*)d_in[12];
    const float* bb2 = (const float*)d_in[13];
    const float* m2  = (const float*)d_in[14];
    const float* v2  = (const float*)d_in[15];
    const float* w3l = (const float*)d_in[16];
    const float* w3r = (const float*)d_in[17];
    const float* b3  = (const float*)d_in[18];
    const float* fcw = (const float*)d_in[19];
    const float* fcb = (const float*)d_in[20];

    char* ws = (char*)d_ws;
    size_t off = 0;
    auto alloc = [&](size_t bytes) -> void* {
        void* p = ws + off;
        off += (bytes + 255) & ~(size_t)255;
        return p;
    };
    int*   deg    = (int*)alloc((size_t)NNODES * 4);
    int*   offs   = (int*)alloc((size_t)(NNODES + 1) * 4);
    int*   bs     = (int*)alloc((size_t)NCHB * 4);
    int*   bse    = (int*)alloc((size_t)NCHB * 4);
    float* deginv = (float*)alloc((size_t)NNODES * 4);
    int*   csr    = (int*)alloc((size_t)(NEDGES + 64) * 4);  // +64 pad
    bf16*  t2     = (bf16*)alloc((size_t)NNODES * 64 * 2);
    float* r2     = (float*)alloc((size_t)NNODES * 64 * 4);
    bf16*  t3     = (bf16*)alloc((size_t)NNODES * 32 * 2);
    float* r3     = (float*)alloc((size_t)NNODES * 32 * 4);

    hipMemsetAsync(deg, 0, (size_t)NNODES * 4, stream);

    k_deg<<<(NEDGES / 4 + 255) / 256, 256, 0, stream>>>((const int4*)dst, deg);
    k_blocksum<<<NCHB, 256, 0, stream>>>(deg, bs);
    k_scanbs<<<1, 512, 0, stream>>>(bs, bse, offs);
    k_offsets<<<NCHB, 256, 0, stream>>>(deg, bse, offs, deginv);
    k_fill<<<(NEDGES / 4 + 255) / 256, 256, 0, stream>>>((const int4*)src, (const int4*)dst,
                                                         offs, deg, csr);

    k_layer1<<<768, 256, 0, stream>>>(x, csr, offs, deginv,
                                      w1l, w1r, b1, g1, bb1, m1, v1,
                                      w2l, w2r, b2, g2, bb2, m2, v2,
                                      t2, r2);
    k_layer2<<<1024, 256, 0, stream>>>(t2, r2, csr, offs, deginv,
                                       w3l, w3r, b3, t3, r3);
    k_layer3<<<(NNODES + 3) / 4, 256, 0, stream>>>(t3, r3, csr, offs, deginv,
                                                   fcw, fcb, (float*)d_out);
}